// Round 13
// baseline (126.576 us; speedup 1.0000x reference)
//
#include <hip/hip_runtime.h>

#define H 64
#define W 64
#define C 256
#define O 256
#define NB 8
#define KK 9
#define HW 4096
#define KTOT 2304   // 9*256

typedef _Float16 f16;
typedef _Float16 f16x8 __attribute__((ext_vector_type(8)));
typedef float f32x4 __attribute__((ext_vector_type(4)));

// barrier with LDS-only drain (global loads stay in flight)
#define BAR_FULL() do {                                            \
    __builtin_amdgcn_sched_barrier(0);                             \
    asm volatile("s_waitcnt lgkmcnt(0)" ::: "memory");             \
    __builtin_amdgcn_s_barrier();                                  \
    __builtin_amdgcn_sched_barrier(0);                             \
} while (0)
#define BAR_RAW() do {                                             \
    __builtin_amdgcn_sched_barrier(0);                             \
    asm volatile("" ::: "memory");                                 \
    __builtin_amdgcn_s_barrier();                                  \
    __builtin_amdgcn_sched_barrier(0);                             \
} while (0)

// ---------------- K0: fused weight prep
__global__ void wprep_kernel(const float* __restrict__ cw, const float* __restrict__ ow,
                             f16* __restrict__ Wt2, f16* __restrict__ Wo2) {
    int tid = blockIdx.x * blockDim.x + threadIdx.x;
    if (tid < O * KTOT) {
        int o = tid / KTOT;
        int r = tid - o * KTOT;
        int k = r >> 8;
        int c = r & 255;
        Wt2[tid] = (f16)cw[o * KTOT + c * 9 + k];
    } else if (tid < O * KTOT + 32 * KTOT) {
        int t2 = tid - O * KTOT;
        int m = t2 / KTOT;
        int r = t2 - m * KTOT;
        int tap = r >> 8;
        int c = r & 255;
        Wo2[t2] = (m < 18) ? (f16)ow[(m * 256 + c) * 9 + tap] : (f16)0.f;
    }
}

// ---------------- transpose x (B,C,HW) fp32 -> x_t (B,HW,C) f16
__global__ __launch_bounds__(256) void transpose_x_kernel(
    const float* __restrict__ x, f16* __restrict__ xt)
{
    __shared__ float tile[64][65];
    int b   = blockIdx.z;
    int yx0 = blockIdx.x * 64;
    int c0  = blockIdx.y * 64;
    int t = threadIdx.x;
    int j = t & 63, q = t >> 6;
    #pragma unroll 4
    for (int i = 0; i < 16; i++) {
        int c = c0 + q * 16 + i;
        tile[q * 16 + i][j] = x[((size_t)(b * C + c)) * HW + yx0 + j];
    }
    __syncthreads();
    #pragma unroll 4
    for (int i = 0; i < 16; i++) {
        int yx = yx0 + q * 16 + i;
        xt[((size_t)(b * HW + yx)) * C + c0 + j] = (f16)tile[j][q * 16 + i];
    }
}

// ---------------- K1: offset conv via direct-conv MFMA (R6-verbatim, proven)
__global__ __launch_bounds__(256, 4) void offset_mfma_kernel(
    const f16* __restrict__ xt, const f16* __restrict__ Wo2,
    const float* __restrict__ ob, float* __restrict__ params)
{
    int bid = blockIdx.x;
    int b  = bid & 7;
    int y0 = (bid >> 3) * 2;
    int t  = threadIdx.x;
    int l  = t & 63;
    int wv = t >> 6;
    const int ln = l & 15;
    const int kh = (l >> 4) * 8;

    __shared__ f16 xs[4][66][36];
    __shared__ f16 Ws[9][32][36];

    f32x4 acc[2][2];
    #pragma unroll
    for (int i = 0; i < 2; i++)
        #pragma unroll
        for (int j = 0; j < 2; j++) acc[i][j] = (f32x4)0.f;

    const f16* xtb = xt + (size_t)b * HW * C;

    for (int chunk = 0; chunk < 8; chunk++) {
        int cbase = chunk * 32;
        BAR_RAW();
        for (int pos = t; pos < 264; pos += 256) {
            int row = pos / 66;
            int col = pos - row * 66;
            int y  = y0 - 1 + row;
            int xg = col - 1;
            f16x8 v0 = (f16x8)(f16)0.f, v1 = v0, v2 = v0, v3 = v0;
            if (y >= 0 && y < H && xg >= 0 && xg < W) {
                const f16* src = xtb + (size_t)(y * W + xg) * C + cbase;
                v0 = *(const f16x8*)(src);
                v1 = *(const f16x8*)(src + 8);
                v2 = *(const f16x8*)(src + 16);
                v3 = *(const f16x8*)(src + 24);
            }
            *(f16x8*)&xs[row][col][0]  = v0;
            *(f16x8*)&xs[row][col][8]  = v1;
            *(f16x8*)&xs[row][col][16] = v2;
            *(f16x8*)&xs[row][col][24] = v3;
        }
        for (int g = t; g < 1152; g += 256) {
            int tap = g >> 7;
            int rem = g & 127;
            int mm  = rem >> 2;
            int c8  = (rem & 3) * 8;
            *(f16x8*)&Ws[tap][mm][c8] =
                *(const f16x8*)&Wo2[(size_t)mm * KTOT + tap * 256 + cbase + c8];
        }
        BAR_FULL();

        #pragma unroll
        for (int tap = 0; tap < 9; tap++) {
            const int tr = tap / 3, tc = tap % 3;
            f16x8 a0 = *(const f16x8*)&Ws[tap][ln][kh];
            f16x8 a1 = *(const f16x8*)&Ws[tap][16 + ln][kh];
            #pragma unroll
            for (int pf = 0; pf < 2; pf++) {
                int pxb = wv * 32 + pf * 16;
                int rl  = pxb >> 6;
                int cx  = (pxb & 63) + tc + ln;
                f16x8 bf = *(const f16x8*)&xs[rl + tr][cx][kh];
                acc[0][pf] = __builtin_amdgcn_mfma_f32_16x16x32_f16(a0, bf, acc[0][pf], 0, 0, 0);
                acc[1][pf] = __builtin_amdgcn_mfma_f32_16x16x32_f16(a1, bf, acc[1][pf], 0, 0, 0);
            }
        }
    }

    int q = l >> 4;
    #pragma unroll
    for (int f = 0; f < 2; f++) {
        #pragma unroll
        for (int pr = 0; pr < 2; pr++) {
            int m0 = f * 16 + q * 4 + pr * 2;
            int k  = m0 >> 1;
            if (k > 8) continue;
            float oby = ob[m0];
            float obx = ob[m0 + 1];
            int tr = k / 3, tc = k - tr * 3;
            #pragma unroll
            for (int pf = 0; pf < 2; pf++) {
                int pxl = wv * 32 + pf * 16 + ln;
                int y   = y0 + (pxl >> 6);
                int xp  = pxl & 63;
                float dy = acc[f][pf][pr * 2]     + oby;
                float dx = acc[f][pf][pr * 2 + 1] + obx;
                float py  = (float)(y - 1 + tr) + dy;
                float pxx = (float)(xp - 1 + tc) + dx;
                float y0f = floorf(py), x0f = floorf(pxx);
                float4 prm;
                prm.x = __int_as_float((int)y0f);
                prm.y = __int_as_float((int)x0f);
                prm.z = py - y0f;
                prm.w = pxx - x0f;
                ((float4*)params)[((size_t)(b * KK + k)) * HW + y * W + xp] = prm;
            }
        }
    }
}

// ---------------- K2: fused gather + f16 MFMA GEMM
// block: 256 o x 128 px, 512 threads (8 waves of 64o x 64px), K-chunk 32
// grid 256 = 1 block/CU; W staged via LDS
// NEW (single variable vs R12): nontemporal loads on gather + W streams
//   (zero L1 reuse -> bypass L1 allocation; tests the 3.3 cyc/line constant)
#define SPAD 40
#define WPAD 40
__global__ __launch_bounds__(512, 2) void deform_mfma_kernel(
    const f16* __restrict__ xt, const f16* __restrict__ Wt2,
    const float* __restrict__ params, const float* __restrict__ cb,
    float* __restrict__ out)
{
    int bid = blockIdx.x;
    int b  = bid & 7;              // XCD-affine batch
    int p0 = (bid >> 3) * 128;
    int t  = threadIdx.x;
    int l  = t & 63;
    int wv = t >> 6;

    __shared__ f16 St[2][128][SPAD];   // 20.5 KB
    __shared__ f16 Wl[2][256][WPAD];   // 41.0 KB

    f32x4 acc[4][4];
    #pragma unroll
    for (int i = 0; i < 4; i++)
        #pragma unroll
        for (int j = 0; j < 4; j++) acc[i][j] = (f32x4)0.f;

    const int px  = t >> 2;          // pixel [0,128)
    const int cg  = (t & 3) * 8;     // 8-ch slice within 32-chunk
    const int ows = t >> 2;          // W staging row [0,128); also +128
    const int wcs = (t & 3) * 8;     // W staging col {0,8,16,24} elements (16B)
    const f16* xtb = xt + (size_t)b * HW * C;
    const float4* params4 = (const float4*)params;

    const int wo = (wv >> 1) * 64;   // wave o-block (4 of them)
    const int wp = (wv & 1) * 64;    // wave px-block (2 of them)
    const int ln = l & 15;
    const int kh = (l >> 4) * 8;

    int i00n, i01n, i10n, i11n;
    float w00n, w01n, w10n, w11n;

#define RECOMP(kk_) do {                                                      \
    float4 prm = params4[((size_t)(b * KK + (kk_))) * HW + p0 + px];          \
    int y0 = __float_as_int(prm.x);                                           \
    int x0 = __float_as_int(prm.y);                                           \
    float wy = prm.z, wx = prm.w;                                             \
    int y1 = y0 + 1, x1 = x0 + 1;                                             \
    bool vy0 = (y0 >= 0) & (y0 < H);                                          \
    bool vy1 = (y1 >= 0) & (y1 < H);                                          \
    bool vx0 = (x0 >= 0) & (x0 < W);                                          \
    bool vx1 = (x1 >= 0) & (x1 < W);                                          \
    w00n = (vy0 & vx0) ? (1.f - wy) * (1.f - wx) : 0.f;                       \
    w01n = (vy0 & vx1) ? (1.f - wy) * wx : 0.f;                               \
    w10n = (vy1 & vx0) ? wy * (1.f - wx) : 0.f;                               \
    w11n = (vy1 & vx1) ? wy * wx : 0.f;                                       \
    int yc0 = min(max(y0, 0), H - 1), yc1 = min(max(y1, 0), H - 1);           \
    int xc0 = min(max(x0, 0), W - 1), xc1 = min(max(x1, 0), W - 1);           \
    i00n = yc0 * W + xc0; i01n = yc0 * W + xc1;                               \
    i10n = yc1 * W + xc0; i11n = yc1 * W + xc1;                               \
} while (0)

// 4 corner gathers (16B each) + 2 W staging loads — all nontemporal (L1 bypass)
#define ISSUE(G00, G01, G10, G11, WA, WB,                                     \
              V00, V01, V10, V11, chn_) do {                                  \
    int kk_ = (chn_) >> 3; int cb_ = ((chn_) & 7) * 32;                       \
    const f16* xb_ = xtb + cb_ + cg;                                          \
    G00 = __builtin_nontemporal_load((const f16x8*)(xb_ + (size_t)i00n * C)); \
    G01 = __builtin_nontemporal_load((const f16x8*)(xb_ + (size_t)i01n * C)); \
    G10 = __builtin_nontemporal_load((const f16x8*)(xb_ + (size_t)i10n * C)); \
    G11 = __builtin_nontemporal_load((const f16x8*)(xb_ + (size_t)i11n * C)); \
    const f16* wb_ = Wt2 + kk_ * 256 + cb_ + wcs;                             \
    WA = __builtin_nontemporal_load((const f16x8*)(wb_ + (size_t)ows * KTOT));\
    WB = __builtin_nontemporal_load((const f16x8*)(wb_ + (size_t)(ows + 128) * KTOT)); \
    V00 = w00n; V01 = w01n; V10 = w10n; V11 = w11n;                           \
} while (0)

// interp in f32 (R6-proven), store St + stage W to LDS
#define CONSUME(G00, G01, G10, G11, WA, WB, V00, V01, V10, V11, buf_) do {    \
    f16x8 r_;                                                                 \
    _Pragma("unroll")                                                         \
    for (int j_ = 0; j_ < 8; j_++) {                                          \
        float s_ = V00 * (float)G00[j_] + V01 * (float)G01[j_] +              \
                   V10 * (float)G10[j_] + V11 * (float)G11[j_];               \
        r_[j_] = (f16)s_;                                                     \
    }                                                                         \
    *(f16x8*)&St[buf_][px][cg] = r_;                                          \
    *(f16x8*)&Wl[buf_][ows][wcs]       = WA;                                  \
    *(f16x8*)&Wl[buf_][ows + 128][wcs] = WB;                                  \
} while (0)

#define MF(a_, bfr_, f_, p_) \
    acc[f_][p_] = __builtin_amdgcn_mfma_f32_16x16x32_f16(a_, bfr_, acc[f_][p_], 0, 0, 0)

#define DOMFMA(buf_) do {                                                     \
    f16x8 af0 = *(const f16x8*)&Wl[buf_][wo +  0 + ln][kh];                   \
    f16x8 af1 = *(const f16x8*)&Wl[buf_][wo + 16 + ln][kh];                   \
    f16x8 af2 = *(const f16x8*)&Wl[buf_][wo + 32 + ln][kh];                   \
    f16x8 af3 = *(const f16x8*)&Wl[buf_][wo + 48 + ln][kh];                   \
    f16x8 bf0 = *(const f16x8*)&St[buf_][wp +  0 + ln][kh];                   \
    f16x8 bf1 = *(const f16x8*)&St[buf_][wp + 16 + ln][kh];                   \
    f16x8 bf2 = *(const f16x8*)&St[buf_][wp + 32 + ln][kh];                   \
    f16x8 bf3 = *(const f16x8*)&St[buf_][wp + 48 + ln][kh];                   \
    MF(af0, bf0, 0, 0); MF(af0, bf1, 0, 1); MF(af0, bf2, 0, 2); MF(af0, bf3, 0, 3); \
    MF(af1, bf0, 1, 0); MF(af1, bf1, 1, 1); MF(af1, bf2, 1, 2); MF(af1, bf3, 1, 3); \
    MF(af2, bf0, 2, 0); MF(af2, bf1, 2, 1); MF(af2, bf2, 2, 2); MF(af2, bf3, 2, 3); \
    MF(af3, bf0, 3, 0); MF(af3, bf1, 3, 1); MF(af3, bf2, 3, 2); MF(af3, bf3, 3, 3); \
} while (0)

    f16x8 ga00, ga01, ga10, ga11, gb00, gb01, gb10, gb11;
    f16x8 wa0, wa1, wb0, wb1;
    float va00, va01, va10, va11, vb00, vb01, vb10, vb11;

    RECOMP(0);
    ISSUE(ga00, ga01, ga10, ga11, wa0, wa1,
          va00, va01, va10, va11, 0);

    for (int ch = 0; ch < 72; ch += 2) {
        {
            int chn = ch + 1;
            if ((chn & 7) == 0) RECOMP(chn >> 3);
            ISSUE(gb00, gb01, gb10, gb11, wb0, wb1,
                  vb00, vb01, vb10, vb11, chn);
        }
        CONSUME(ga00, ga01, ga10, ga11, wa0, wa1,
                va00, va01, va10, va11, 0);
        BAR_FULL();
        DOMFMA(0);
        {
            int chn = ch + 2 < 72 ? ch + 2 : 71;
            if ((chn & 7) == 0) RECOMP(chn >> 3);
            ISSUE(ga00, ga01, ga10, ga11, wa0, wa1,
                  va00, va01, va10, va11, chn);
        }
        CONSUME(gb00, gb01, gb10, gb11, wb0, wb1,
                vb00, vb01, vb10, vb11, 1);
        BAR_FULL();
        DOMFMA(1);
    }

    // epilogue: bias + store (D: row=(l>>4)*4+r -> o, col=l&15 -> p)
    #pragma unroll
    for (int mf = 0; mf < 4; mf++) {
        #pragma unroll
        for (int rr = 0; rr < 4; rr++) {
            int o = wo + mf * 16 + (l >> 4) * 4 + rr;
            float bias = cb[o];
            #pragma unroll
            for (int nf = 0; nf < 4; nf++) {
                int p = p0 + wp + nf * 16 + ln;
                out[((size_t)(b * O + o)) * HW + p] = acc[mf][nf][rr] + bias;
            }
        }
    }
#undef RECOMP
#undef ISSUE
#undef CONSUME
#undef MF
#undef DOMFMA
}

extern "C" void kernel_launch(void* const* d_in, const int* in_sizes, int n_in,
                              void* d_out, int out_size, void* d_ws, size_t ws_size,
                              hipStream_t stream) {
    const float* x  = (const float*)d_in[0];
    const float* ow = (const float*)d_in[1];
    const float* ob = (const float*)d_in[2];
    const float* cw = (const float*)d_in[3];
    const float* cb = (const float*)d_in[4];
    float* out = (float*)d_out;

    char* ws = (char*)d_ws;
    float* params = (float*)ws;                         // 4,718,592 B
    f16*   Wt2    = (f16*)(ws + 4718592);               // 1,179,648 B
    f16*   xt16   = (f16*)(ws + 4718592 + 1179648);     // 16,777,216 B
    f16*   Wo2    = (f16*)(ws + 4718592 + 1179648 + 16777216); // 147,456 B

    wprep_kernel<<<(O * KTOT + 32 * KTOT + 255) / 256, 256, 0, stream>>>(cw, ow, Wt2, Wo2);
    transpose_x_kernel<<<dim3(64, 4, NB), 256, 0, stream>>>(x, xt16);
    offset_mfma_kernel<<<256, 256, 0, stream>>>(xt16, Wo2, ob, params);
    deform_mfma_kernel<<<256, 512, 0, stream>>>(xt16, Wt2, params, cb, out);
}

// Round 15
// 101.651 us; speedup vs baseline: 1.2452x; 1.2452x over previous
//
#include <hip/hip_runtime.h>

#define H 64
#define W 64
#define C 256
#define O 256
#define NB 8
#define KK 9
#define HW 4096
#define KTOT 2304   // 9*256

typedef _Float16 f16;
typedef _Float16 f16x8 __attribute__((ext_vector_type(8)));
typedef float f32x4 __attribute__((ext_vector_type(4)));

// barrier with LDS-only drain (global loads stay in flight)
#define BAR_FULL() do {                                            \
    __builtin_amdgcn_sched_barrier(0);                             \
    asm volatile("s_waitcnt lgkmcnt(0)" ::: "memory");             \
    __builtin_amdgcn_s_barrier();                                  \
    __builtin_amdgcn_sched_barrier(0);                             \
} while (0)
#define BAR_RAW() do {                                             \
    __builtin_amdgcn_sched_barrier(0);                             \
    asm volatile("" ::: "memory");                                 \
    __builtin_amdgcn_s_barrier();                                  \
    __builtin_amdgcn_sched_barrier(0);                             \
} while (0)

// ---------------- K0: fused weight prep (R12-proven)
__global__ void wprep_kernel(const float* __restrict__ cw, const float* __restrict__ ow,
                             f16* __restrict__ Wt2, f16* __restrict__ Wo2) {
    int tid = blockIdx.x * blockDim.x + threadIdx.x;
    if (tid < O * KTOT) {
        int o = tid / KTOT;
        int r = tid - o * KTOT;
        int k = r >> 8;
        int c = r & 255;
        Wt2[tid] = (f16)cw[o * KTOT + c * 9 + k];
    } else if (tid < O * KTOT + 32 * KTOT) {
        int t2 = tid - O * KTOT;
        int m = t2 / KTOT;
        int r = t2 - m * KTOT;
        int tap = r >> 8;
        int c = r & 255;
        Wo2[t2] = (m < 18) ? (f16)ow[(m * 256 + c) * 9 + tap] : (f16)0.f;
    }
}

// ---------------- transpose x (B,C,HW) fp32 -> x_t (B,HW,C) f16
__global__ __launch_bounds__(256) void transpose_x_kernel(
    const float* __restrict__ x, f16* __restrict__ xt)
{
    __shared__ float tile[64][65];
    int b   = blockIdx.z;
    int yx0 = blockIdx.x * 64;
    int c0  = blockIdx.y * 64;
    int t = threadIdx.x;
    int j = t & 63, q = t >> 6;
    #pragma unroll 4
    for (int i = 0; i < 16; i++) {
        int c = c0 + q * 16 + i;
        tile[q * 16 + i][j] = x[((size_t)(b * C + c)) * HW + yx0 + j];
    }
    __syncthreads();
    #pragma unroll 4
    for (int i = 0; i < 16; i++) {
        int yx = yx0 + q * 16 + i;
        xt[((size_t)(b * HW + yx)) * C + c0 + j] = (f16)tile[j][q * 16 + i];
    }
}

// ---------------- K1: offset conv via direct-conv MFMA (R6-verbatim, proven)
__global__ __launch_bounds__(256, 4) void offset_mfma_kernel(
    const f16* __restrict__ xt, const f16* __restrict__ Wo2,
    const float* __restrict__ ob, float* __restrict__ params)
{
    int bid = blockIdx.x;
    int b  = bid & 7;
    int y0 = (bid >> 3) * 2;
    int t  = threadIdx.x;
    int l  = t & 63;
    int wv = t >> 6;
    const int ln = l & 15;
    const int kh = (l >> 4) * 8;

    __shared__ f16 xs[4][66][36];
    __shared__ f16 Ws[9][32][36];

    f32x4 acc[2][2];
    #pragma unroll
    for (int i = 0; i < 2; i++)
        #pragma unroll
        for (int j = 0; j < 2; j++) acc[i][j] = (f32x4)0.f;

    const f16* xtb = xt + (size_t)b * HW * C;

    for (int chunk = 0; chunk < 8; chunk++) {
        int cbase = chunk * 32;
        BAR_RAW();
        for (int pos = t; pos < 264; pos += 256) {
            int row = pos / 66;
            int col = pos - row * 66;
            int y  = y0 - 1 + row;
            int xg = col - 1;
            f16x8 v0 = (f16x8)(f16)0.f, v1 = v0, v2 = v0, v3 = v0;
            if (y >= 0 && y < H && xg >= 0 && xg < W) {
                const f16* src = xtb + (size_t)(y * W + xg) * C + cbase;
                v0 = *(const f16x8*)(src);
                v1 = *(const f16x8*)(src + 8);
                v2 = *(const f16x8*)(src + 16);
                v3 = *(const f16x8*)(src + 24);
            }
            *(f16x8*)&xs[row][col][0]  = v0;
            *(f16x8*)&xs[row][col][8]  = v1;
            *(f16x8*)&xs[row][col][16] = v2;
            *(f16x8*)&xs[row][col][24] = v3;
        }
        for (int g = t; g < 1152; g += 256) {
            int tap = g >> 7;
            int rem = g & 127;
            int mm  = rem >> 2;
            int c8  = (rem & 3) * 8;
            *(f16x8*)&Ws[tap][mm][c8] =
                *(const f16x8*)&Wo2[(size_t)mm * KTOT + tap * 256 + cbase + c8];
        }
        BAR_FULL();

        #pragma unroll
        for (int tap = 0; tap < 9; tap++) {
            const int tr = tap / 3, tc = tap % 3;
            f16x8 a0 = *(const f16x8*)&Ws[tap][ln][kh];
            f16x8 a1 = *(const f16x8*)&Ws[tap][16 + ln][kh];
            #pragma unroll
            for (int pf = 0; pf < 2; pf++) {
                int pxb = wv * 32 + pf * 16;
                int rl  = pxb >> 6;
                int cx  = (pxb & 63) + tc + ln;
                f16x8 bf = *(const f16x8*)&xs[rl + tr][cx][kh];
                acc[0][pf] = __builtin_amdgcn_mfma_f32_16x16x32_f16(a0, bf, acc[0][pf], 0, 0, 0);
                acc[1][pf] = __builtin_amdgcn_mfma_f32_16x16x32_f16(a1, bf, acc[1][pf], 0, 0, 0);
            }
        }
    }

    int q = l >> 4;
    #pragma unroll
    for (int f = 0; f < 2; f++) {
        #pragma unroll
        for (int pr = 0; pr < 2; pr++) {
            int m0 = f * 16 + q * 4 + pr * 2;
            int k  = m0 >> 1;
            if (k > 8) continue;
            float oby = ob[m0];
            float obx = ob[m0 + 1];
            int tr = k / 3, tc = k - tr * 3;
            #pragma unroll
            for (int pf = 0; pf < 2; pf++) {
                int pxl = wv * 32 + pf * 16 + ln;
                int y   = y0 + (pxl >> 6);
                int xp  = pxl & 63;
                float dy = acc[f][pf][pr * 2]     + oby;
                float dx = acc[f][pf][pr * 2 + 1] + obx;
                float py  = (float)(y - 1 + tr) + dy;
                float pxx = (float)(xp - 1 + tc) + dx;
                float y0f = floorf(py), x0f = floorf(pxx);
                float4 prm;
                prm.x = __int_as_float((int)y0f);
                prm.y = __int_as_float((int)x0f);
                prm.z = py - y0f;
                prm.w = pxx - x0f;
                ((float4*)params)[((size_t)(b * KK + k)) * HW + y * W + xp] = prm;
            }
        }
    }
}

// ---------------- K2: fused gather + f16 MFMA GEMM
// block: 256 o x 128 px, 512 threads (8 waves of 64o x 64px), K-chunk 32
// grid 256 = 1 block/CU; W staged via LDS; R12-proven structure.
// Single variable vs R12: packed-f16 interp in CONSUME (R4/R5-proven precision)
#define SPAD 40
#define WPAD 40
__global__ __launch_bounds__(512, 2) void deform_mfma_kernel(
    const f16* __restrict__ xt, const f16* __restrict__ Wt2,
    const float* __restrict__ params, const float* __restrict__ cb,
    float* __restrict__ out)
{
    int bid = blockIdx.x;
    int b  = bid & 7;              // XCD-affine batch
    int p0 = (bid >> 3) * 128;
    int t  = threadIdx.x;
    int l  = t & 63;
    int wv = t >> 6;

    __shared__ f16 St[2][128][SPAD];   // 20.5 KB
    __shared__ f16 Wl[2][256][WPAD];   // 41.0 KB

    f32x4 acc[4][4];
    #pragma unroll
    for (int i = 0; i < 4; i++)
        #pragma unroll
        for (int j = 0; j < 4; j++) acc[i][j] = (f32x4)0.f;

    const int px  = t >> 2;          // pixel [0,128)
    const int cg  = (t & 3) * 8;     // 8-ch slice within 32-chunk
    const int ows = t >> 2;          // W staging row [0,128); also +128
    const int wcs = (t & 3) * 8;     // W staging col (16B)
    const f16* xtb = xt + (size_t)b * HW * C;
    const float4* params4 = (const float4*)params;

    const int wo = (wv >> 1) * 64;   // wave o-block (4 of them)
    const int wp = (wv & 1) * 64;    // wave px-block (2 of them)
    const int ln = l & 15;
    const int kh = (l >> 4) * 8;

    int i00n, i01n, i10n, i11n;
    float w00n, w01n, w10n, w11n;

#define RECOMP(kk_) do {                                                      \
    float4 prm = params4[((size_t)(b * KK + (kk_))) * HW + p0 + px];          \
    int y0 = __float_as_int(prm.x);                                           \
    int x0 = __float_as_int(prm.y);                                           \
    float wy = prm.z, wx = prm.w;                                             \
    int y1 = y0 + 1, x1 = x0 + 1;                                             \
    bool vy0 = (y0 >= 0) & (y0 < H);                                          \
    bool vy1 = (y1 >= 0) & (y1 < H);                                          \
    bool vx0 = (x0 >= 0) & (x0 < W);                                          \
    bool vx1 = (x1 >= 0) & (x1 < W);                                          \
    w00n = (vy0 & vx0) ? (1.f - wy) * (1.f - wx) : 0.f;                       \
    w01n = (vy0 & vx1) ? (1.f - wy) * wx : 0.f;                               \
    w10n = (vy1 & vx0) ? wy * (1.f - wx) : 0.f;                               \
    w11n = (vy1 & vx1) ? wy * wx : 0.f;                                       \
    int yc0 = min(max(y0, 0), H - 1), yc1 = min(max(y1, 0), H - 1);           \
    int xc0 = min(max(x0, 0), W - 1), xc1 = min(max(x1, 0), W - 1);           \
    i00n = yc0 * W + xc0; i01n = yc0 * W + xc1;                               \
    i10n = yc1 * W + xc0; i11n = yc1 * W + xc1;                               \
} while (0)

// 4 corner gathers (16B each) + 2 W staging loads (R12-proven, normal loads)
#define ISSUE(G00, G01, G10, G11, WA, WB,                                     \
              V00, V01, V10, V11, chn_) do {                                  \
    int kk_ = (chn_) >> 3; int cb_ = ((chn_) & 7) * 32;                       \
    const f16* xb_ = xtb + cb_ + cg;                                          \
    G00 = *(const f16x8*)(xb_ + (size_t)i00n * C);                            \
    G01 = *(const f16x8*)(xb_ + (size_t)i01n * C);                            \
    G10 = *(const f16x8*)(xb_ + (size_t)i10n * C);                            \
    G11 = *(const f16x8*)(xb_ + (size_t)i11n * C);                            \
    const f16* wb_ = Wt2 + kk_ * 256 + cb_ + wcs;                             \
    WA = *(const f16x8*)(wb_ + (size_t)ows * KTOT);                           \
    WB = *(const f16x8*)(wb_ + (size_t)(ows + 128) * KTOT);                   \
    V00 = w00n; V01 = w01n; V10 = w10n; V11 = w11n;                           \
} while (0)

// packed f16 interp (R4/R5-proven precision, absmax 0.0156), store St + stage W
#define CONSUME(G00, G01, G10, G11, WA, WB, V00, V01, V10, V11, buf_) do {    \
    f16 h00 = (f16)V00, h01 = (f16)V01, h10 = (f16)V10, h11 = (f16)V11;       \
    f16x8 r_ = G00 * h00 + G01 * h01 + G10 * h10 + G11 * h11;                 \
    *(f16x8*)&St[buf_][px][cg] = r_;                                          \
    *(f16x8*)&Wl[buf_][ows][wcs]       = WA;                                  \
    *(f16x8*)&Wl[buf_][ows + 128][wcs] = WB;                                  \
} while (0)

#define MF(a_, bfr_, f_, p_) \
    acc[f_][p_] = __builtin_amdgcn_mfma_f32_16x16x32_f16(a_, bfr_, acc[f_][p_], 0, 0, 0)

#define DOMFMA(buf_) do {                                                     \
    f16x8 af0 = *(const f16x8*)&Wl[buf_][wo +  0 + ln][kh];                   \
    f16x8 af1 = *(const f16x8*)&Wl[buf_][wo + 16 + ln][kh];                   \
    f16x8 af2 = *(const f16x8*)&Wl[buf_][wo + 32 + ln][kh];                   \
    f16x8 af3 = *(const f16x8*)&Wl[buf_][wo + 48 + ln][kh];                   \
    f16x8 bf0 = *(const f16x8*)&St[buf_][wp +  0 + ln][kh];                   \
    f16x8 bf1 = *(const f16x8*)&St[buf_][wp + 16 + ln][kh];                   \
    f16x8 bf2 = *(const f16x8*)&St[buf_][wp + 32 + ln][kh];                   \
    f16x8 bf3 = *(const f16x8*)&St[buf_][wp + 48 + ln][kh];                   \
    MF(af0, bf0, 0, 0); MF(af0, bf1, 0, 1); MF(af0, bf2, 0, 2); MF(af0, bf3, 0, 3); \
    MF(af1, bf0, 1, 0); MF(af1, bf1, 1, 1); MF(af1, bf2, 1, 2); MF(af1, bf3, 1, 3); \
    MF(af2, bf0, 2, 0); MF(af2, bf1, 2, 1); MF(af2, bf2, 2, 2); MF(af2, bf3, 2, 3); \
    MF(af3, bf0, 3, 0); MF(af3, bf1, 3, 1); MF(af3, bf2, 3, 2); MF(af3, bf3, 3, 3); \
} while (0)

    f16x8 ga00, ga01, ga10, ga11, gb00, gb01, gb10, gb11;
    f16x8 wa0, wa1, wb0, wb1;
    float va00, va01, va10, va11, vb00, vb01, vb10, vb11;

    RECOMP(0);
    ISSUE(ga00, ga01, ga10, ga11, wa0, wa1,
          va00, va01, va10, va11, 0);

    for (int ch = 0; ch < 72; ch += 2) {
        {
            int chn = ch + 1;
            if ((chn & 7) == 0) RECOMP(chn >> 3);
            ISSUE(gb00, gb01, gb10, gb11, wb0, wb1,
                  vb00, vb01, vb10, vb11, chn);
        }
        CONSUME(ga00, ga01, ga10, ga11, wa0, wa1,
                va00, va01, va10, va11, 0);
        BAR_FULL();
        DOMFMA(0);
        {
            int chn = ch + 2 < 72 ? ch + 2 : 71;
            if ((chn & 7) == 0) RECOMP(chn >> 3);
            ISSUE(ga00, ga01, ga10, ga11, wa0, wa1,
                  va00, va01, va10, va11, chn);
        }
        CONSUME(gb00, gb01, gb10, gb11, wb0, wb1,
                vb00, vb01, vb10, vb11, 1);
        BAR_FULL();
        DOMFMA(1);
    }

    // epilogue: bias + store (D: row=(l>>4)*4+r -> o, col=l&15 -> p)
    #pragma unroll
    for (int mf = 0; mf < 4; mf++) {
        #pragma unroll
        for (int rr = 0; rr < 4; rr++) {
            int o = wo + mf * 16 + (l >> 4) * 4 + rr;
            float bias = cb[o];
            #pragma unroll
            for (int nf = 0; nf < 4; nf++) {
                int p = p0 + wp + nf * 16 + ln;
                out[((size_t)(b * O + o)) * HW + p] = acc[mf][nf][rr] + bias;
            }
        }
    }
#undef RECOMP
#undef ISSUE
#undef CONSUME
#undef MF
#undef DOMFMA
}

extern "C" void kernel_launch(void* const* d_in, const int* in_sizes, int n_in,
                              void* d_out, int out_size, void* d_ws, size_t ws_size,
                              hipStream_t stream) {
    const float* x  = (const float*)d_in[0];
    const float* ow = (const float*)d_in[1];
    const float* ob = (const float*)d_in[2];
    const float* cw = (const float*)d_in[3];
    const float* cb = (const float*)d_in[4];
    float* out = (float*)d_out;

    char* ws = (char*)d_ws;
    float* params = (float*)ws;                         // 4,718,592 B
    f16*   Wt2    = (f16*)(ws + 4718592);               // 1,179,648 B
    f16*   xt16   = (f16*)(ws + 4718592 + 1179648);     // 16,777,216 B
    f16*   Wo2    = (f16*)(ws + 4718592 + 1179648 + 16777216); // 147,456 B

    wprep_kernel<<<(O * KTOT + 32 * KTOT + 255) / 256, 256, 0, stream>>>(cw, ow, Wt2, Wo2);
    transpose_x_kernel<<<dim3(64, 4, NB), 256, 0, stream>>>(x, xt16);
    offset_mfma_kernel<<<256, 256, 0, stream>>>(xt16, Wo2, ob, params);
    deform_mfma_kernel<<<256, 512, 0, stream>>>(xt16, Wt2, params, cb, out);
}